// Round 3
// baseline (322.294 us; speedup 1.0000x reference)
//
#include <hip/hip_runtime.h>

// ContractExpand, fused-across-scales:
//   out[n,b,l,:] = relu(seg_r(x)[b, l/r, :] @ W[n]^T + bias[n]) / r,  r={1,2,4,10,25}
// Block = (b, 100-row L-chunk): reads its x chunk ONCE from HBM.
//   phase 1: seg-sums for r=2/4/10/25 (89 rows) fp32 -> bf16 into swizzled LDS.
//   phase 2: 285 (mtile,ntile) MFMA pairs over 8 waves; r=1 A-frags straight
//            from global x (L2-hot) with in-reg bf16 convert; fused epilogue
//            with r-way repeated stores.

typedef short bf16x8 __attribute__((ext_vector_type(8)));
typedef float f32x4  __attribute__((ext_vector_type(4)));

namespace {
constexpr int D    = 300;
constexpr int LSEQ = 800;
constexpr int KP   = 320;   // padded K (10 steps of 32)
constexpr int NP   = 320;   // padded N for Wb rows
constexpr size_t TOTX = (size_t)64 * LSEQ * D;
// LDS seg rows: r2 base 0 (50 rows), r4 base 50 (25), r25 base 75 (4), r10 base 79 (10)
// max ds_read row = 79 + 15 = 94 -> allocate 95 rows * 640 B = 60.8 KB
constexpr int SEGROWS = 95;
}

__device__ __forceinline__ unsigned short f2bf(float f) {
  unsigned u = __float_as_uint(f);
  u += 0x7fffu + ((u >> 16) & 1u);   // RNE
  return (unsigned short)(u >> 16);
}

__global__ void convert_w(const float* __restrict__ W, short* __restrict__ Wb) {
  int idx = blockIdx.x * 256 + threadIdx.x;
  if (idx >= 5 * NP * KP) return;
  int n   = idx / (NP * KP);
  int rem = idx - n * NP * KP;
  int c = rem / KP, k = rem - c * KP;
  float v = (c < D && k < D) ? W[(size_t)n * D * D + (size_t)c * D + k] : 0.f;
  Wb[idx] = (short)f2bf(v);
}

__global__ __launch_bounds__(512, 4)
void ce_fused2(const float* __restrict__ x, const short* __restrict__ Wb,
               const float* __restrict__ bias, float* __restrict__ out) {
  __shared__ short seg[SEGROWS * 320];
  char* __restrict__ segb = (char*)seg;

  const int bid = blockIdx.x;
  const int b   = bid >> 3;      // batch
  const int c   = bid & 7;       // 100-row chunk of L
  const int tid = threadIdx.x;

  // ---- phase 1: seg-sums for scales r=2,4,10,25 into swizzled bf16 LDS ----
  // items: (scale-local row) x (40 chunks of 8 cols); r2 first = the HBM touch.
  for (int it = tid; it < 3560; it += 512) {
    int s, loc;
    if (it < 2000)      { s = 1; loc = it; }
    else if (it < 3000) { s = 2; loc = it - 2000; }
    else if (it < 3400) { s = 3; loc = it - 3000; }
    else                { s = 4; loc = it - 3400; }
    const int r    = (s == 1) ? 2 : (s == 2) ? 4 : (s == 3) ? 10 : 25;
    const int base = (s == 1) ? 0 : (s == 2) ? 50 : (s == 3) ? 79 : 75;
    const int row  = loc / 40;
    const int ch   = loc - row * 40;
    const int k0   = ch * 8;
    float sm[8];
    #pragma unroll
    for (int j = 0; j < 8; ++j) sm[j] = 0.f;
    if (k0 < 300) {
      const int l0 = c * 100 + row * r;
      const float* xp = x + ((size_t)(b * LSEQ + l0)) * D + k0;
      if (k0 <= 292) {               // full 8 cols valid
        for (int q = 0; q < r; ++q) {
          const float4 v0 = *(const float4*)(xp + (size_t)q * D);
          const float4 v1 = *(const float4*)(xp + (size_t)q * D + 4);
          sm[0] += v0.x; sm[1] += v0.y; sm[2] += v0.z; sm[3] += v0.w;
          sm[4] += v1.x; sm[5] += v1.y; sm[6] += v1.z; sm[7] += v1.w;
        }
      } else {                       // k0 == 296: cols 296..299 only
        for (int q = 0; q < r; ++q) {
          const float4 v0 = *(const float4*)(xp + (size_t)q * D);
          sm[0] += v0.x; sm[1] += v0.y; sm[2] += v0.z; sm[3] += v0.w;
        }
      }
    }
    const int lrow = base + row;
    bf16x8 p;
    #pragma unroll
    for (int j = 0; j < 8; ++j) p[j] = (short)f2bf(sm[j]);
    const int boff = (lrow * 640 + k0 * 2) ^ ((lrow & 7) << 4);
    *(bf16x8*)(segb + boff) = p;
  }
  __syncthreads();

  // ---- phase 2: 285 (mtile, ntile) pairs, heavy scales first ----
  const int wv   = tid >> 6;
  const int lane = tid & 63;
  const int cr   = lane & 15;   // A row / B col / C col
  const int kh   = lane >> 4;   // k-half (k = kh*8 + j); C row = kh*4 + reg

  for (int p = wv; p < 285; p += 8) {
    int S, mt, nt;
    if (p < 19)       { S = 4; mt = 0; nt = p; }
    else if (p < 38)  { S = 3; mt = 0; nt = p - 19; }
    else if (p < 76)  { int q = p - 38;  S = 2; mt = q / 19; nt = q - (q / 19) * 19; }
    else if (p < 152) { int q = p - 76;  S = 1; mt = q / 19; nt = q - (q / 19) * 19; }
    else              { int q = p - 152; S = 0; mt = q / 19; nt = q - (q / 19) * 19; }
    const int r    = (S == 0) ? 1 : (S == 1) ? 2 : (S == 2) ? 4 : (S == 3) ? 10 : 25;
    const int rows = (S == 0) ? 100 : (S == 1) ? 50 : (S == 2) ? 25 : (S == 3) ? 10 : 4;
    const short* __restrict__ Wn = Wb + (size_t)S * NP * KP;
    const size_t wrow = (size_t)(nt * 16 + cr) * KP;

    f32x4 acc = (f32x4){0.f, 0.f, 0.f, 0.f};

    if (S == 0) {
      // A = x rows themselves, straight from global (L2-hot), convert in-reg
      const int l_row = c * 100 + mt * 16 + cr;
      const int l_eff = l_row > (LSEQ - 1) ? (LSEQ - 1) : l_row;   // garbage row, masked at store
      const size_t rowbase = ((size_t)b * LSEQ + l_eff) * D;
      #pragma unroll
      for (int ks = 0; ks < 10; ++ks) {
        const int kk = ks * 32 + kh * 8;
        const size_t fl = rowbase + kk;
        float4 v0 = {0.f, 0.f, 0.f, 0.f}, v1 = {0.f, 0.f, 0.f, 0.f};
        if (fl + 4 <= TOTX) v0 = *(const float4*)(x + fl);
        if (fl + 8 <= TOTX) v1 = *(const float4*)(x + fl + 4);
        bf16x8 a;
        a[0] = (short)f2bf(v0.x); a[1] = (short)f2bf(v0.y);
        a[2] = (short)f2bf(v0.z); a[3] = (short)f2bf(v0.w);
        a[4] = (short)f2bf(v1.x); a[5] = (short)f2bf(v1.y);
        a[6] = (short)f2bf(v1.z); a[7] = (short)f2bf(v1.w);
        const bf16x8 bf = *(const bf16x8*)(Wn + wrow + kk);
        acc = __builtin_amdgcn_mfma_f32_16x16x32_bf16(a, bf, acc, 0, 0, 0);
      }
    } else {
      const int base = (S == 1) ? 0 : (S == 2) ? 50 : (S == 3) ? 79 : 75;
      const int lrow = base + mt * 16 + cr;
      const int swz  = (lrow & 7) << 4;
      #pragma unroll
      for (int ks = 0; ks < 10; ++ks) {
        const int boff = (lrow * 640 + ks * 64 + kh * 16) ^ swz;
        const bf16x8 a  = *(const bf16x8*)(segb + boff);
        const bf16x8 bf = *(const bf16x8*)(Wn + wrow + ks * 32 + kh * 8);
        acc = __builtin_amdgcn_mfma_f32_16x16x32_bf16(a, bf, acc, 0, 0, 0);
      }
    }

    // epilogue: bias + relu + /r, repeat r times
    const float inv_r = 1.0f / (float)r;
    const int col = nt * 16 + cr;
    if (col < D) {
      const float bv = bias[S * D + col];
      #pragma unroll
      for (int j = 0; j < 4; ++j) {
        const int grp = mt * 16 + kh * 4 + j;
        if (grp < rows) {
          const float y  = fmaxf(acc[j] + bv, 0.f) * inv_r;
          const int  l0  = c * 100 + grp * r;
          float* __restrict__ op = out + ((size_t)(S * 64 + b) * LSEQ + l0) * D + col;
          for (int q = 0; q < r; ++q) op[(size_t)q * D] = y;
        }
      }
    }
  }
}

extern "C" void kernel_launch(void* const* d_in, const int* in_sizes, int n_in,
                              void* d_out, int out_size, void* d_ws, size_t ws_size,
                              hipStream_t stream) {
  const float* x    = (const float*)d_in[0];  // [64, 800, 300]
  const float* W    = (const float*)d_in[1];  // [5, 300, 300]
  const float* bias = (const float*)d_in[2];  // [5, 300]
  float* out        = (float*)d_out;          // [5, 64, 800, 300]
  short* Wb         = (short*)d_ws;           // [5][320][320] bf16, ~1 MB

  convert_w<<<(5 * NP * KP + 255) / 256, 256, 0, stream>>>(W, Wb);
  ce_fused2<<<512, 512, 0, stream>>>(x, Wb, bias, out);
}

// Round 4
// 143.060 us; speedup vs baseline: 2.2529x; 2.2529x over previous
//
#include <hip/hip_runtime.h>

// ContractExpand via bf16 MFMA, round-2 geometry + LDS-staged vectorized stores:
//   out[n,b,l,:] = relu(seg_r(x)[b, l/r, :] @ W[n]^T + bias[n]) / r,  r={25,10,4,2,1}
// Per block (32 group-rows of one scale):
//   p1: seg-sum fp32 -> bf16 XOR-swizzled LDS [32][320]   (R unrolled via template)
//   p2: 4 waves x (2 mtile x 5 ntile) x 10 K-steps mfma_f32_16x16x32_bf16,
//       B-frags straight from global bf16 W (L2-resident)
//   p3: bias+relu+/r -> fp32 LDS [32][304] (union with seg buffer)
//   p4: all 256 threads stream output incl. r-repeats as coalesced float4

typedef short bf16x8 __attribute__((ext_vector_type(8)));
typedef float f32x4  __attribute__((ext_vector_type(4)));

namespace {
constexpr int D    = 300;
constexpr int LSEQ = 800;
constexpr int KP   = 320;   // padded K (10 steps of 32)
constexpr int NP   = 320;   // padded N rows of Wb
constexpr int CSTR = 304;   // cout row stride (floats)
constexpr int SMEM_BYTES = 32 * CSTR * 4;   // 38912 B > 32*320*2 = 20480 B
}

__device__ __forceinline__ unsigned short f2bf(float f) {
  unsigned u = __float_as_uint(f);
  u += 0x7fffu + ((u >> 16) & 1u);   // RNE
  return (unsigned short)(u >> 16);
}

__global__ void convert_w(const float* __restrict__ W, short* __restrict__ Wb) {
  int idx = blockIdx.x * 256 + threadIdx.x;
  if (idx >= 5 * NP * KP) return;
  int n   = idx / (NP * KP);
  int rem = idx - n * NP * KP;
  int c = rem / KP, k = rem - c * KP;
  float v = (c < D && k < D) ? W[(size_t)n * D * D + (size_t)c * D + k] : 0.f;
  Wb[idx] = (short)f2bf(v);
}

template<int N, int R, int G>
__device__ __forceinline__ void ce_body(const int tile, char* __restrict__ smem,
    const float* __restrict__ x, const short* __restrict__ Wb,
    const float* __restrict__ bias, float* __restrict__ out) {
  const int tid = threadIdx.x;
  const int m0  = tile * 32;                 // first group-row; M_total = 64*G

  // ---- phase 1: seg-sums fp32 -> bf16 swizzled LDS [32 rows][320 cols] ----
  #pragma unroll
  for (int it = 0; it < 5; ++it) {
    const int cidx = tid + it * 256;         // 0..1279 = 32 rows x 40 chunks
    const int row  = cidx / 40;
    const int k0   = (cidx - row * 40) * 8;
    float s[8];
    #pragma unroll
    for (int j = 0; j < 8; ++j) s[j] = 0.f;
    if (k0 < D) {
      const int m   = m0 + row;
      const int bb  = m / G;
      const int grp = m - bb * G;
      const float* xp = x + ((size_t)(bb * LSEQ + grp * R)) * D + k0;
      if (k0 <= D - 8) {
        #pragma unroll
        for (int q = 0; q < R; ++q) {
          const float4 v0 = *(const float4*)(xp + (size_t)q * D);
          const float4 v1 = *(const float4*)(xp + (size_t)q * D + 4);
          s[0] += v0.x; s[1] += v0.y; s[2] += v0.z; s[3] += v0.w;
          s[4] += v1.x; s[5] += v1.y; s[6] += v1.z; s[7] += v1.w;
        }
      } else {                               // k0 == 296: cols 296..299 only
        #pragma unroll
        for (int q = 0; q < R; ++q) {
          const float4 v0 = *(const float4*)(xp + (size_t)q * D);
          s[0] += v0.x; s[1] += v0.y; s[2] += v0.z; s[3] += v0.w;
        }
      }
    }
    bf16x8 p;
    #pragma unroll
    for (int j = 0; j < 8; ++j) p[j] = (short)f2bf(s[j]);
    const int boff = (row * 640 + k0 * 2) ^ ((row & 7) << 4);
    *(bf16x8*)(smem + boff) = p;
  }
  __syncthreads();

  // ---- phase 2: MFMA.  A from LDS, B from global bf16 W (L2-hot) ----
  const int wv   = tid >> 6;
  const int lane = tid & 63;
  const int cr   = lane & 15;    // A row / B col / C col
  const int kh   = lane >> 4;    // k-half; C row = kh*4 + reg

  f32x4 acc[2][5];
  #pragma unroll
  for (int mt = 0; mt < 2; ++mt)
    #pragma unroll
    for (int t = 0; t < 5; ++t) acc[mt][t] = (f32x4){0.f, 0.f, 0.f, 0.f};

  const short* __restrict__ Wn = Wb + (size_t)N * NP * KP;
  const int swz0 = (cr & 7) << 4;            // same key for rows cr and 16+cr

  #pragma unroll
  for (int ks = 0; ks < 10; ++ks) {
    const int b0 = (cr * 640        + ks * 64 + kh * 16) ^ swz0;
    const int b1 = ((16 + cr) * 640 + ks * 64 + kh * 16) ^ swz0;
    const bf16x8 a0 = *(const bf16x8*)(smem + b0);
    const bf16x8 a1 = *(const bf16x8*)(smem + b1);
    #pragma unroll
    for (int t = 0; t < 5; ++t) {
      const int col = (wv * 5 + t) * 16 + cr;
      const bf16x8 bf = *(const bf16x8*)(Wn + (size_t)col * KP + ks * 32 + kh * 8);
      acc[0][t] = __builtin_amdgcn_mfma_f32_16x16x32_bf16(a0, bf, acc[0][t], 0, 0, 0);
      acc[1][t] = __builtin_amdgcn_mfma_f32_16x16x32_bf16(a1, bf, acc[1][t], 0, 0, 0);
    }
  }
  __syncthreads();                           // seg reads done; reuse LDS for cout

  // ---- phase 3: bias + relu + /R -> fp32 LDS tile [32][CSTR] ----
  float* __restrict__ cout = (float*)smem;
  const float inv_r = 1.0f / (float)R;
  #pragma unroll
  for (int t = 0; t < 5; ++t) {
    const int col = (wv * 5 + t) * 16 + cr;
    if (col < D) {
      const float bv = bias[N * D + col];
      #pragma unroll
      for (int mt = 0; mt < 2; ++mt)
        #pragma unroll
        for (int j = 0; j < 4; ++j) {
          const int row = mt * 16 + kh * 4 + j;
          cout[row * CSTR + col] = fmaxf(acc[mt][t][j] + bv, 0.f) * inv_r;
        }
    }
  }
  __syncthreads();

  // ---- phase 4: coalesced float4 stores, repeats included ----
  constexpr int TOTAL = 32 * R * 75;         // (group-rows x repeats) x float4-chunks
  for (int i = tid; i < TOTAL; i += 256) {
    const int rowrep = i / 75;
    const int chunk  = i - rowrep * 75;
    const int ml     = rowrep / R;
    const int q      = rowrep - ml * R;
    const int m      = m0 + ml;
    const int bb     = m / G;
    const int grp    = m - bb * G;
    const f32x4 v = *(const f32x4*)(cout + ml * CSTR + chunk * 4);
    float* __restrict__ op =
        out + ((size_t)((N * 64 + bb) * LSEQ) + grp * R + q) * D + chunk * 4;
    *(f32x4*)op = v;
  }
}

__global__ __launch_bounds__(256, 4)
void ce_mfma4(const float* __restrict__ x, const short* __restrict__ Wb,
              const float* __restrict__ bias, float* __restrict__ out) {
  __shared__ __align__(16) char smem[SMEM_BYTES];
  const int bid = blockIdx.x;
  if (bid < 64)        ce_body<4, 25, 32 >(bid,        smem, x, Wb, bias, out);
  else if (bid < 224)  ce_body<3, 10, 80 >(bid - 64,   smem, x, Wb, bias, out);
  else if (bid < 624)  ce_body<2, 4, 200 >(bid - 224,  smem, x, Wb, bias, out);
  else if (bid < 1424) ce_body<1, 2, 400 >(bid - 624,  smem, x, Wb, bias, out);
  else                 ce_body<0, 1, 800 >(bid - 1424, smem, x, Wb, bias, out);
}

extern "C" void kernel_launch(void* const* d_in, const int* in_sizes, int n_in,
                              void* d_out, int out_size, void* d_ws, size_t ws_size,
                              hipStream_t stream) {
  const float* x    = (const float*)d_in[0];  // [64, 800, 300]
  const float* W    = (const float*)d_in[1];  // [5, 300, 300]
  const float* bias = (const float*)d_in[2];  // [5, 300]
  float* out        = (float*)d_out;          // [5, 64, 800, 300]
  short* Wb         = (short*)d_ws;           // [5][320][320] bf16, ~1 MB

  convert_w<<<(5 * NP * KP + 255) / 256, 256, 0, stream>>>(W, Wb);
  ce_mfma4<<<3024, 256, 0, stream>>>(x, Wb, bias, out);
}